// Round 8
// baseline (199.170 us; speedup 1.0000x reference)
//
#include <hip/hip_runtime.h>
#include <hip/hip_fp16.h>

// GAT layer (2 heads, N=100k, D=64, E=1.7M), fp32. 5 kernels:
//   k_front   : per-node scores (4 nodes/wave, 16 lanes/node, DPP-cheap
//               reduce) + bf16 cast of x || per-tile bucket hist
//   k_col_scan: per-bucket exclusive prefix over tiles -> tbase, totals
//   k_binning : LDS counting-sort of tiles into bucket runs (hist reused
//               from tcnt; bbase computed in-block, block 0 publishes)
//   k_rowsort : per-bucket (256 rows) row sort + e-values + rowsums + coef
//               -> writes scol (col<<5, row-grouped) + ecoef (half)
//   k_gather  : per-node wave gather, NO LDS/exp/barriers: streams
//               (col,coef), quarter-wave x gather, 4 edges/iteration
// out[i,:] = sum_e coef[e]*x[col[e],:], coef = 0.5*(e0/rs0 + e1/rs1).
// LESSONS: (R4) xh must be 128B-aligned or FETCH x1.8. (R6) never trade
// gather occupancy for locality (29% occ = 2x slower). (R7) gather is
// L2-miss latency bound, not VALU bound -> move VALU work to sort side.

#define D 64
#define ALPHA 0.2f
#define BSHIFT 8        // rows per bucket = 256
#define BROWS 256
#define MAXBUK 512      // supports N <= 131072
#define TILE 2048       // edges per tile
#define PK2 17          // pack = (row & 255) << 17 | col  (col < 2^17)
#define M17 ((1u << PK2) - 1u)
#define CAPE 6144       // LDS edge capacity per 256-row bucket (mean ~4440)

__device__ __forceinline__ unsigned bf16rne(float f) {
    unsigned u = __float_as_uint(f);
    u += 0x7fffu + ((u >> 16) & 1u);
    return u >> 16;
}
__device__ __forceinline__ float lrexp(float sc) {
    return __expf(sc > 0.f ? sc : ALPHA * sc);
}
__device__ __forceinline__ unsigned packe(float e0, float e1) {
    __half2 h = __floats2half2_rn(e0, e1);
    return *reinterpret_cast<unsigned*>(&h);
}
__device__ __forceinline__ float2 unpacke(unsigned u) {
    __half2 h = *reinterpret_cast<__half2*>(&u);
    return __half22float2(h);
}

// blocks [0, nblkA): scores+cast, 16 nodes/block (4 per wave, 16 lanes each).
// blocks [nblkA, nblkA+NT): per-tile bucket histogram -> tcnt (u16).
__global__ __launch_bounds__(256) void k_front(
    const float* __restrict__ x, const float* __restrict__ W,
    const float* __restrict__ a, float4* __restrict__ s,
    unsigned* __restrict__ xh2, const int* __restrict__ row,
    unsigned short* __restrict__ tcnt, int N, int E, int nblkA)
{
    __shared__ int h[MAXBUK];
    if ((int)blockIdx.x < nblkA) {
        int wid  = (blockIdx.x * 256 + threadIdx.x) >> 6;   // global wave id
        int lane = threadIdx.x & 63;
        int node = wid * 4 + (lane >> 4);
        int f4   = lane & 15;          // feature quad: feats 4*f4 .. 4*f4+3
        if (node >= N) return;
        const float4* x4 = (const float4*)x;
        const float4* W4 = (const float4*)W;
        const float4* A4 = (const float4*)a;
        float4 v  = x4[(size_t)node * 16 + f4];
        // bf16 cast: 2 packed uints per lane, coalesced per 16-lane group
        unsigned u01 = (bf16rne(v.y) << 16) | bf16rne(v.x);
        unsigned u23 = (bf16rne(v.w) << 16) | bf16rne(v.z);
        *(uint2*)(xh2 + (size_t)node * 32 + 2 * f4) = make_uint2(u01, u23);
        float4 w0 = W4[f4], w1 = W4[16 + f4];
        float4 a0 = A4[f4], a1 = A4[16 + f4], a2 = A4[32 + f4], a3 = A4[48 + f4];
        float4 h0 = make_float4(v.x * w0.x, v.y * w0.y, v.z * w0.z, v.w * w0.w);
        float4 h1 = make_float4(v.x * w1.x, v.y * w1.y, v.z * w1.z, v.w * w1.w);
        float t0 = h0.x * a0.x + h0.y * a0.y + h0.z * a0.z + h0.w * a0.w;
        float t1 = h0.x * a1.x + h0.y * a1.y + h0.z * a1.z + h0.w * a1.w;
        float t2 = h1.x * a2.x + h1.y * a2.y + h1.z * a2.z + h1.w * a2.w;
        float t3 = h1.x * a3.x + h1.y * a3.y + h1.z * a3.z + h1.w * a3.w;
#pragma unroll
        for (int off = 1; off < 16; off <<= 1) {   // within-16-lane (DPP-cheap)
            t0 += __shfl_xor(t0, off);
            t1 += __shfl_xor(t1, off);
            t2 += __shfl_xor(t2, off);
            t3 += __shfl_xor(t3, off);
        }
        if (f4 == 0) s[node] = make_float4(t0, t1, t2, t3);
    } else {
        int tile = blockIdx.x - nblkA;
        int t = threadIdx.x, base = tile * TILE;
        int cnt = E - base; if (cnt > TILE) cnt = TILE;
        h[t] = 0; h[t + 256] = 0;
        __syncthreads();
        for (int i = t; i < cnt; i += 256) atomicAdd(&h[row[base + i] >> BSHIFT], 1);
        __syncthreads();
        tcnt[(size_t)tile * MAXBUK + t]       = (unsigned short)h[t];
        tcnt[(size_t)tile * MAXBUK + t + 256] = (unsigned short)h[t + 256];
    }
}

// MAXBUK blocks; block b: exclusive prefix of tcnt[:,b] over tiles (NT<=1024)
__global__ __launch_bounds__(256) void k_col_scan(
    const unsigned short* __restrict__ tcnt, int* __restrict__ tbase,
    int* __restrict__ bcnt, int NT, int nbuk)
{
    int b = blockIdx.x, t = threadIdx.x;
    if (b >= nbuk) { if (t == 0) bcnt[b] = 0; return; }
    __shared__ int wsum[256];
    int t4 = t * 4;
    int v0 = (t4     < NT) ? tcnt[(size_t)(t4    ) * MAXBUK + b] : 0;
    int v1 = (t4 + 1 < NT) ? tcnt[(size_t)(t4 + 1) * MAXBUK + b] : 0;
    int v2 = (t4 + 2 < NT) ? tcnt[(size_t)(t4 + 2) * MAXBUK + b] : 0;
    int v3 = (t4 + 3 < NT) ? tcnt[(size_t)(t4 + 3) * MAXBUK + b] : 0;
    int sv = v0 + v1 + v2 + v3;
    wsum[t] = sv;
    __syncthreads();
    for (int off = 1; off < 256; off <<= 1) {
        int add = (t >= off) ? wsum[t - off] : 0;
        __syncthreads();
        wsum[t] += add;
        __syncthreads();
    }
    int run = wsum[t] - sv;
    if (t4     < NT) { tbase[(size_t)(t4    ) * MAXBUK + b] = run; run += v0; }
    if (t4 + 1 < NT) { tbase[(size_t)(t4 + 1) * MAXBUK + b] = run; run += v1; }
    if (t4 + 2 < NT) { tbase[(size_t)(t4 + 2) * MAXBUK + b] = run; run += v2; }
    if (t4 + 3 < NT) { tbase[(size_t)(t4 + 3) * MAXBUK + b] = run; run += v3; }
    if (t == 255) bcnt[b] = wsum[255];
}

// deterministic tile binning; hist from tcnt; bbase from in-block scan of bcnt
__global__ __launch_bounds__(256) void k_binning(
    const int* __restrict__ row, const int* __restrict__ col,
    const unsigned short* __restrict__ tcnt, const int* __restrict__ bcnt,
    const int* __restrict__ tbase, unsigned* __restrict__ ebuf,
    int* __restrict__ bbase_g, int E)
{
    __shared__ int lrow[TILE];
    __shared__ int lcol[TILE];
    __shared__ int st[MAXBUK];
    __shared__ int gb[MAXBUK];
    __shared__ int cur[MAXBUK];
    __shared__ int w2[256];
    int t = threadIdx.x;
    int tile = blockIdx.x;
    int base = tile * TILE;
    int cnt = E - base; if (cnt > TILE) cnt = TILE;

    // scan A: this tile's bucket histogram (from tcnt, 2/thread)
    int h0 = tcnt[(size_t)tile * MAXBUK + 2 * t];
    int h1 = tcnt[(size_t)tile * MAXBUK + 2 * t + 1];
    int sv = h0 + h1;
    w2[t] = sv;
    __syncthreads();
    for (int off = 1; off < 256; off <<= 1) {
        int add = (t >= off) ? w2[t - off] : 0;
        __syncthreads();
        w2[t] += add;
        __syncthreads();
    }
    int run = w2[t] - sv;
    st[2 * t] = run;       st[2 * t + 1] = run + h0;
    cur[2 * t] = run;      cur[2 * t + 1] = run + h0;
    __syncthreads();   // before reusing w2

    // scan B: global bucket bases from bcnt
    int b0 = bcnt[2 * t], b1 = bcnt[2 * t + 1];
    int sb = b0 + b1;
    w2[t] = sb;
    __syncthreads();
    for (int off = 1; off < 256; off <<= 1) {
        int add = (t >= off) ? w2[t - off] : 0;
        __syncthreads();
        w2[t] += add;
        __syncthreads();
    }
    int runb = w2[t] - sb;
    gb[2 * t]     = runb      + tbase[(size_t)tile * MAXBUK + 2 * t];
    gb[2 * t + 1] = runb + b0 + tbase[(size_t)tile * MAXBUK + 2 * t + 1];
    if (tile == 0) {
        bbase_g[2 * t] = runb; bbase_g[2 * t + 1] = runb + b0;
        if (t == 255) bbase_g[512] = runb + b0 + b1;
    }
    __syncthreads();

    for (int i = t; i < cnt; i += 256) {
        int r = row[base + i], c = col[base + i];
        int p = atomicAdd(&cur[r >> BSHIFT], 1);
        lrow[p] = r; lcol[p] = c;
    }
    __syncthreads();

    for (int i = t; i < cnt; i += 256) {
        int rr = lrow[i];
        int bb = rr >> BSHIFT;
        ebuf[gb[bb] + (i - st[bb])] =
            ((unsigned)(rr & (BROWS - 1)) << PK2) | (unsigned)lcol[i];
    }
}

// one block per 256-row bucket (1024 thr): row sort + e-values + rowsums,
// writes row-grouped scol (col<<5) + ecoef (half), offsets, counts.
__global__ __launch_bounds__(1024) void k_rowsort(
    const unsigned* __restrict__ ebuf, const int* __restrict__ bbase,
    const float4* __restrict__ s, int* __restrict__ offsets,
    int* __restrict__ counts, unsigned* __restrict__ scol,
    __half* __restrict__ ecoef, int N)
{
    __shared__ unsigned lpk[CAPE];
    __shared__ unsigned lev[CAPE];     // half2(e0,e1)
    __shared__ int   hist[BROWS];
    __shared__ int   offs[BROWS];
    __shared__ int   cursor[BROWS];
    __shared__ float rs0[BROWS], rs1[BROWS];
    __shared__ float rsx[BROWS], rsz[BROWS];
    __shared__ int   wsum[256];
    int b = blockIdx.x, t = threadIdx.x;
    int lo = b << BSHIFT;
    int s0 = bbase[b], s1 = bbase[b + 1];
    int seg = s1 - s0;

    if (t < BROWS) {
        int g = lo + t;
        float4 f = (g < N) ? s[g] : make_float4(0.f, 0.f, 0.f, 0.f);
        rsx[t] = f.x; rsz[t] = f.z;
        hist[t] = 0; rs0[t] = 0.f; rs1[t] = 0.f;
    }
    __syncthreads();

    for (int i = s0 + t; i < s1; i += 1024)
        atomicAdd(&hist[ebuf[i] >> PK2], 1);
    __syncthreads();

    int a = 0;
    if (t < BROWS) { a = hist[t]; wsum[t] = a; }
    __syncthreads();
    for (int off = 1; off < 256; off <<= 1) {
        int add = 0;
        if (t < BROWS && t >= off) add = wsum[t - off];
        __syncthreads();
        if (t < BROWS) wsum[t] += add;
        __syncthreads();
    }
    if (t < BROWS) { offs[t] = wsum[t] - a; cursor[t] = wsum[t] - a; }
    __syncthreads();

    if (seg <= CAPE) {   // fast path (always, for this input)
        for (int i = s0 + t; i < s1; i += 1024) {
            unsigned pk = ebuf[i];
            int r = pk >> PK2, c = (int)(pk & M17);
            float4 sc = s[c];
            float e0 = lrexp(rsx[r] + sc.y);
            float e1 = lrexp(rsz[r] + sc.w);
            atomicAdd(&rs0[r], e0);
            atomicAdd(&rs1[r], e1);
            int p = atomicAdd(&cursor[r], 1);
            lpk[p] = pk; lev[p] = packe(e0, e1);
        }
        __syncthreads();
        if (t < BROWS) {
            rs0[t] = 0.5f / rs0[t]; rs1[t] = 0.5f / rs1[t];
            int rg = lo + t;
            if (rg < N) { offsets[rg] = s0 + offs[t]; counts[rg] = hist[t]; }
        }
        __syncthreads();
        for (int i = t; i < seg; i += 1024) {
            unsigned pk = lpk[i];
            int r = pk >> PK2;
            float2 ef = unpacke(lev[i]);
            float coef = rs0[r] * ef.x + rs1[r] * ef.y;
            scol[s0 + i]  = (pk & M17) << 5;
            ecoef[s0 + i] = __float2half(coef);
        }
    } else {   // streaming fallback (degree blowup insurance; order nondeterministic)
        for (int i = s0 + t; i < s1; i += 1024) {
            unsigned pk = ebuf[i];
            int r = pk >> PK2, c = (int)(pk & M17);
            float4 sc = s[c];
            atomicAdd(&rs0[r], lrexp(rsx[r] + sc.y));
            atomicAdd(&rs1[r], lrexp(rsz[r] + sc.w));
        }
        __syncthreads();
        if (t < BROWS) {
            rs0[t] = 0.5f / rs0[t]; rs1[t] = 0.5f / rs1[t];
            int rg = lo + t;
            if (rg < N) { offsets[rg] = s0 + offs[t]; counts[rg] = hist[t]; }
        }
        __syncthreads();
        for (int i = s0 + t; i < s1; i += 1024) {
            unsigned pk = ebuf[i];
            int r = pk >> PK2, c = (int)(pk & M17);
            float4 sc = s[c];
            float coef = rs0[r] * lrexp(rsx[r] + sc.y)
                       + rs1[r] * lrexp(rsz[r] + sc.w);
            int p = atomicAdd(&cursor[r], 1);
            scol[s0 + p]  = (unsigned)c << 5;
            ecoef[s0 + p] = __float2half(coef);
        }
    }
}

// 4 nodes/block, 1 wave/node, no LDS/barriers. Four 16-lane quarters
// cooperate on the node: quarter q takes edges q, q+4, ...; each lane
// reads uint2 (4 bf16 feats) -> 4 edges per 128B-coalesced x access.
__global__ __launch_bounds__(256) void k_gather(
    const unsigned* __restrict__ xh2, const int* __restrict__ offsets,
    const int* __restrict__ counts, const unsigned* __restrict__ scol,
    const __half* __restrict__ ecoef, float* __restrict__ out, int N)
{
    int w    = threadIdx.x >> 6;
    int lane = threadIdx.x & 63;
    int n    = blockIdx.x * 4 + w;
    if (n >= N) return;
    int start = offsets[n], cnt = counts[n];
    int q  = lane >> 4;      // edge parity mod 4
    int li = lane & 15;      // feature-quad index
    float a0 = 0.f, a1 = 0.f, a2 = 0.f, a3 = 0.f;
    for (int kk = q; kk < cnt; kk += 4) {
        unsigned cb = scol[start + kk];            // col<<5 (broadcast load)
        float cf = __half2float(ecoef[start + kk]);
        uint2 u = *(const uint2*)(xh2 + cb + 2 * li);
        a0 += cf * __uint_as_float(u.x << 16);
        a1 += cf * __uint_as_float(u.x & 0xffff0000u);
        a2 += cf * __uint_as_float(u.y << 16);
        a3 += cf * __uint_as_float(u.y & 0xffff0000u);
    }
    a0 += __shfl_xor(a0, 16); a0 += __shfl_xor(a0, 32);
    a1 += __shfl_xor(a1, 16); a1 += __shfl_xor(a1, 32);
    a2 += __shfl_xor(a2, 16); a2 += __shfl_xor(a2, 32);
    a3 += __shfl_xor(a3, 16); a3 += __shfl_xor(a3, 32);
    if (q == 0)
        ((float4*)(out + (size_t)n * D))[li] = make_float4(a0, a1, a2, a3);
}

extern "C" void kernel_launch(void* const* d_in, const int* in_sizes, int n_in,
                              void* d_out, int out_size, void* d_ws, size_t ws_size,
                              hipStream_t stream)
{
    const float* x  = (const float*)d_in[0];
    const int*   ei = (const int*)d_in[1];
    const float* W  = (const float*)d_in[2];
    const float* a  = (const float*)d_in[3];
    float*       out = (float*)d_out;
    int N = in_sizes[0] / D;
    int E = in_sizes[1] / 2;
    const int* row = ei;
    const int* col = ei + E;

    int NBUK = (N + BROWS - 1) >> BSHIFT;   // 391 for N=100000 (<= MAXBUK)
    int NT   = (E + TILE - 1) / TILE;       // 831 for E=1.7M (<= 1024)

    // workspace (~35 MB): every array 256B-aligned (xh alignment critical)
    uintptr_t wp = (uintptr_t)d_ws;
    auto alloc = [&wp](size_t bytes) -> void* {
        wp = (wp + 255) & ~(uintptr_t)255;
        void* p = (void*)wp;
        wp += bytes;
        return p;
    };
    unsigned*       xh2     = (unsigned*)alloc((size_t)N * 32 * 4);
    float4*         s       = (float4*)alloc((size_t)N * sizeof(float4));
    int*            offsets = (int*)alloc((size_t)N * sizeof(int));
    int*            counts  = (int*)alloc((size_t)N * sizeof(int));
    unsigned*       scol    = (unsigned*)alloc((size_t)E * sizeof(unsigned));
    unsigned*       ebuf    = (unsigned*)alloc((size_t)E * sizeof(unsigned));
    __half*         ecoef   = (__half*)alloc((size_t)E * sizeof(__half));
    int*            tbase   = (int*)alloc((size_t)NT * MAXBUK * sizeof(int));
    int*            bcnt    = (int*)alloc(MAXBUK * sizeof(int));
    int*            bbase   = (int*)alloc((MAXBUK + 4) * sizeof(int));
    unsigned short* tcnt    = (unsigned short*)alloc((size_t)NT * MAXBUK * 2);

    int nblkA = (N + 15) / 16;   // 16 nodes per 256-thread block
    k_front<<<nblkA + NT, 256, 0, stream>>>(x, W, a, s, xh2, row, tcnt, N, E, nblkA);
    k_col_scan<<<MAXBUK, 256, 0, stream>>>(tcnt, tbase, bcnt, NT, NBUK);
    k_binning<<<NT, 256, 0, stream>>>(row, col, tcnt, bcnt, tbase, ebuf, bbase, E);
    k_rowsort<<<NBUK, 1024, 0, stream>>>(ebuf, bbase, s, offsets, counts, scol, ecoef, N);
    k_gather<<<(N + 3) / 4, 256, 0, stream>>>(xh2, offsets, counts, scol, ecoef, out, N);
}